// Round 1
// 355.555 us; speedup vs baseline: 1.2294x; 1.2294x over previous
//
#include <hip/hip_runtime.h>
#include <cstdint>

#define HH 72
#define NR 8
#define NTH 576
#define NBLK 256
#define TT 512

typedef __attribute__((ext_vector_type(8))) _Float16 half8;
typedef __attribute__((ext_vector_type(4))) float f32x4;

#if __has_builtin(__builtin_amdgcn_exp2f)
#define EXP2(x) __builtin_amdgcn_exp2f(x)
#else
#define EXP2(x) exp2f(x)
#endif
#if __has_builtin(__builtin_amdgcn_rcpf)
#define RCP(x) __builtin_amdgcn_rcpf(x)
#else
#define RCP(x) (1.0f/(x))
#endif

__device__ __forceinline__ float fsig(float x) {
  float e = EXP2(x * -1.442695040888963f);
  return RCP(1.0f + e);
}
__device__ __forceinline__ float ftanh(float x) {
  float e = EXP2(x * -2.885390081777927f);
  return fmaf(2.0f, RCP(1.0f + e), -1.0f);
}

// fp32 -> fp16 bits (RNE via v_cvt_f16_f32)
__device__ __forceinline__ unsigned short f2h(float v) {
  union { _Float16 h; unsigned short u; } cv;
  cv.h = (_Float16)v;
  return cv.u;
}

// fragment ushort index for contraction-dim k, batch col m (0..7).
// Layout [kt*4+q][m=8][8]: 8 contiguous fp16 -> one ds_read_b128 per (group,m).
__device__ __forceinline__ int bidx(int k, int m) {
  return ((k >> 5)*4 + ((k >> 3) & 3))*64 + m*8 + (k & 7);
}

__device__ __forceinline__ float cellUpd(float ig, float fg, float gg, float og, float& c) {
  c = fmaf(fsig(fg), c, fsig(ig)*ftanh(gg));
  return fsig(og)*ftanh(c);
}

// accumulate 4 rows: A[r] += W_ * P_[r]
#define FMA4(A, W_, P_) { \
  const float4 _fa = *(const float4*)(P_); \
  A[0] = fmaf((W_), _fa.x, A[0]); A[1] = fmaf((W_), _fa.y, A[1]); \
  A[2] = fmaf((W_), _fa.z, A[2]); A[3] = fmaf((W_), _fa.w, A[3]); }

// counting sort of rows by h_lens (ascending) -> blocks get similar-length rows
__global__ void cfm_sort(const int* __restrict__ h_lens, int* __restrict__ perm) {
  __shared__ int hist[257];
  __shared__ int offs[257];
  const int t = threadIdx.x; // 256
  for (int i = t; i < 257; i += 256) hist[i] = 0;
  __syncthreads();
  for (int i = t; i < 2048; i += 256) {
    int bkt = min(max(h_lens[i] - 256, 0), 256);
    atomicAdd(&hist[bkt], 1);
  }
  __syncthreads();
  if (t == 0) { int s = 0; for (int i = 0; i < 257; ++i) { offs[i] = s; s += hist[i]; } }
  __syncthreads();
  for (int i = t; i < 2048; i += 256) {
    int bkt = min(max(h_lens[i] - 256, 0), 256);
    int pos = atomicAdd(&offs[bkt], 1);
    perm[pos] = i;
  }
}

// NR=8 rows/block, 256 blocks (1/CU), 9 waves x 2 tiles.
// B cols 8..15 read broadcast duplicates of cols 0..7 -> no swizzle fanout;
// every lane owns exactly one (unit,batch) cell update.
__global__ __launch_bounds__(NTH, 2)
void cfm_main(const float* __restrict__ x, const float* __restrict__ rnn,
              const float* __restrict__ deltas, const int* __restrict__ h_lens,
              const float* __restrict__ W_ih, const float* __restrict__ W_hh,
              const float* __restrict__ b_ih, const float* __restrict__ b_hh,
              const float* __restrict__ eW1, const float* __restrict__ eb1,
              const float* __restrict__ eW2, const float* __restrict__ eb2,
              const float* __restrict__ eW3, const float* __restrict__ eb3,
              const float* __restrict__ dW1, const float* __restrict__ db1,
              const float* __restrict__ dW2, const float* __restrict__ db2,
              const float* __restrict__ dW3, const float* __restrict__ db3,
              const int* __restrict__ perm, float* __restrict__ out)
{
  __shared__ __align__(16) unsigned short hF[2][768];  // fp16 [h|xt|pad] B-fragments, dbuf
  __shared__ __align__(16) float gS[2304];             // enc z1S / dec d2S  [n][8]
  __shared__ __align__(16) float rnnS[2336];           // rnn chunk [8][292] ; enc z2S / dec d1S [n][8]
  __shared__ __align__(16) float snapP[NR][HH];
  __shared__ __align__(16) float snapC[NR][HH];
  __shared__ __align__(16) float hS[HH*NR];            // decoder dec_in [u][r]
  __shared__ __align__(16) float xS[8*NR];             // [k][r]
  __shared__ int brS[NR];
  __shared__ int idxS[NR];
  __shared__ float dS[NR];

  const int t  = threadIdx.x;
  const int bb = blockIdx.x;

  for (int i = t; i < 768; i += NTH) ((unsigned*)hF)[i] = 0;  // zero both buffers (pads!)

  if (t < NR) {
    int row = perm ? perm[bb*NR + t] : (bb*NR + t);
    brS[t]  = row;
    idxS[t] = h_lens[row] - 1;   // in [255, 511]
  }
  __syncthreads();

  int maxIdx = idxS[0];
  #pragma unroll
  for (int r = 1; r < NR; ++r) maxIdx = max(maxIdx, idxS[r]);

  const int lane = t & 63;
  const int wv   = t >> 6;                 // 0..8, tiles {2wv, 2wv+1}
  const int col  = lane & 15;
  const int q_a  = lane >> 4;
  const int cL   = col & 7;                // batch col
  const int gHi  = col >> 3;               // which of my wave's 2 tiles
  const int uA   = 4*(2*wv + gHi) + q_a;   // unit owned
  const int cidxE  = idxS[cL];
  const int cidxm1 = cidxE - 1;
  const int ibA  = bidx(uA, cL);
  const int bOff0 = (0*4 + q_a)*64 + cL*8; // broadcast read: col&7
  const int bOff1 = (1*4 + q_a)*64 + cL*8;
  const int bOff2 = (2*4 + q_a)*64 + cL*8;
  float cstA = 0.f;

  // prefetch rnn chunk 0 into regs (1 float4 per thread: 576*16B = 8 rows * 288 floats)
  const int pfR = t / 72;
  const int pfP = t - pfR*72;
  const float4* rnnRow = (const float4*)(rnn + (size_t)brS[pfR]*4608) + pfP;
  float4 pf = rnnRow[0];

  // xt staging lanes: 72 values/step (8 rows x 9 k)
  const bool doXt = (t < 72);
  int xtDst = 0, xtSrc = 0;
  if (doXt) {
    int rX = t / 9, kX = t - rX*9;
    xtDst = bidx(72 + kX, rX);
    xtSrc = rX*292 + kX;          // padded row stride 292 -> spreads banks
  }

  // ---------------- encoder: 8 -> 256 -> 256 -> 64 ----------------
  if (t < 64) { int r = t >> 3, k = t & 7; xS[k*8 + r] = x[brS[r]*8 + k]; }
  __syncthreads();

  float* z1S = gS;   // [n][8]
  if (t < 512) {
    int n = t >> 1, rh = (t & 1)*4;
    float acc[4];
    float b = eb1[n];
    acc[0]=b; acc[1]=b; acc[2]=b; acc[3]=b;
    #pragma unroll
    for (int k = 0; k < 8; ++k) { float w = eW1[n*8 + k]; FMA4(acc, w, &xS[k*8 + rh]); }
    #pragma unroll
    for (int j = 0; j < 4; ++j) z1S[n*8 + rh + j] = ftanh(acc[j]);
  }
  __syncthreads();
  float* z2S = rnnS; // [n][8]
  if (t < 512) {
    int n = t >> 1, rh = (t & 1)*4;
    float acc[4];
    float b = eb2[n];
    acc[0]=b; acc[1]=b; acc[2]=b; acc[3]=b;
    const float4* w4 = (const float4*)(eW2 + n*256);
    #pragma unroll 4
    for (int k4 = 0; k4 < 64; ++k4) {
      float4 w = w4[k4];
      FMA4(acc, w.x, &z1S[(4*k4+0)*8 + rh]);
      FMA4(acc, w.y, &z1S[(4*k4+1)*8 + rh]);
      FMA4(acc, w.z, &z1S[(4*k4+2)*8 + rh]);
      FMA4(acc, w.w, &z1S[(4*k4+3)*8 + rh]);
    }
    #pragma unroll
    for (int j = 0; j < 4; ++j) z2S[n*8 + rh + j] = ftanh(acc[j]);
  }
  __syncthreads();
  if (t < 128) {                       // h0 (linear) -> fragment k = 8+o, buffer 0
    int o = t >> 1, rh = (t & 1)*4;
    float acc[4];
    float b = eb3[o];
    acc[0]=b; acc[1]=b; acc[2]=b; acc[3]=b;
    const float4* w4 = (const float4*)(eW3 + o*256);
    #pragma unroll 4
    for (int k4 = 0; k4 < 64; ++k4) {
      float4 w = w4[k4];
      FMA4(acc, w.x, &z2S[(4*k4+0)*8 + rh]);
      FMA4(acc, w.y, &z2S[(4*k4+1)*8 + rh]);
      FMA4(acc, w.z, &z2S[(4*k4+2)*8 + rh]);
      FMA4(acc, w.w, &z2S[(4*k4+3)*8 + rh]);
    }
    #pragma unroll
    for (int j = 0; j < 4; ++j) hF[0][bidx(8 + o, rh + j)] = f2h(acc[j]);
  } else if (t < 192) {                // x part -> k = 0..7, buffer 0
    int tt2 = t - 128; int r = tt2 >> 3, k = tt2 & 7;
    hF[0][bidx(k, r)] = f2h(xS[k*8 + r]);
  }

  // ---------------- weights as fp16 A-fragments (gate-permuted rows) ----------------
  // n' = 4*unit + gate ; src row = gate*72 + unit. A[row=n'][k], k = kt*32+q_a*8+j.
  half8 Af[2][3];
  f32x4 biasq[2];
  #pragma unroll
  for (int i = 0; i < 2; ++i) {
    int u = 4*(2*wv + i) + q_a;
    biasq[i].x = b_ih[u]       + b_hh[u];
    biasq[i].y = b_ih[72 + u]  + b_hh[72 + u];
    biasq[i].z = b_ih[144 + u] + b_hh[144 + u];
    biasq[i].w = b_ih[216 + u] + b_hh[216 + u];
    int nprime = (2*wv + i)*16 + col;
    int srcrow = (nprime & 3)*72 + (nprime >> 2);
    #pragma unroll
    for (int kt = 0; kt < 3; ++kt) {
      union { unsigned short u16[8]; half8 h; } cw;
      #pragma unroll
      for (int j = 0; j < 8; ++j) {
        int k = kt*32 + q_a*8 + j;
        float v = 0.f;
        if (k < 72)      v = W_hh[srcrow*HH + k];
        else if (k < 81) v = W_ih[srcrow*9 + (k - 72)];
        cw.u16[j] = f2h(v);
      }
      Af[i][kt] = cw.h;
    }
  }

  // ---------------- LSTM over time: one barrier per step ----------------
  // Step PAR: read hF[PAR], write hF[PAR^1]. Chunks are 32 steps, par returns to 0.
#define STEP(PAR) { \
    const unsigned short* hb = &hF[PAR][0]; \
    unsigned short* hn = &hF[(PAR) ^ 1][0]; \
    half8 bf0 = *(const half8*)(hb + bOff0); \
    half8 bf1 = *(const half8*)(hb + bOff1); \
    half8 bf2 = *(const half8*)(hb + bOff2); \
    f32x4 a0 = __builtin_amdgcn_mfma_f32_16x16x32_f16(Af[0][0], bf0, biasq[0], 0, 0, 0); \
    f32x4 a1 = __builtin_amdgcn_mfma_f32_16x16x32_f16(Af[1][0], bf0, biasq[1], 0, 0, 0); \
    a0 = __builtin_amdgcn_mfma_f32_16x16x32_f16(Af[0][1], bf1, a0, 0, 0, 0); \
    a1 = __builtin_amdgcn_mfma_f32_16x16x32_f16(Af[1][1], bf1, a1, 0, 0, 0); \
    a0 = __builtin_amdgcn_mfma_f32_16x16x32_f16(Af[0][2], bf2, a0, 0, 0, 0); \
    a1 = __builtin_amdgcn_mfma_f32_16x16x32_f16(Af[1][2], bf2, a1, 0, 0, 0); \
    float ig = gHi ? a1.x : a0.x; \
    float fg = gHi ? a1.y : a0.y; \
    float gg = gHi ? a1.z : a0.z; \
    float og = gHi ? a1.w : a0.w; \
    float hv = cellUpd(ig, fg, gg, og, cstA); \
    hn[ibA] = f2h(hv); \
    if (step == cidxm1) snapP[cL][uA] = hv; \
    if (step == cidxE)  snapC[cL][uA] = hv; \
    if (doXt && tc < 31) hn[xtDst] = f2h(rnnS[xtSrc + (tc + 1)*9]); \
    __syncthreads(); \
    ++tc; ++step; }

  int step = 0;
  for (int chunk = 0; chunk*32 <= maxIdx; ++chunk) {
    __syncthreads();                         // prior chunk / encoder reads of rnnS done
    *(float4*)&rnnS[pfR*292 + pfP*4] = pf;   // commit prefetched chunk
    if ((chunk + 1)*32 <= maxIdx) pf = rnnRow[(chunk + 1)*72];  // issue next early
    __syncthreads();
    if (doXt) hF[0][xtDst] = f2h(rnnS[xtSrc]);   // xt for first step of chunk (par==0)
    __syncthreads();
    const int lim = min(31, maxIdx - chunk*32);
    int tc = 0;
    while (tc + 1 <= lim) { STEP(0) STEP(1) }
    if (tc <= lim) { STEP(0) }               // odd tail only possible on the last chunk
  }
#undef STEP

  // ---------------- decoder: 72 -> 288 -> 288 -> 8 ----------------
  if (t < NR) dS[t] = deltas[brS[t]*TT + idxS[t]];
  __syncthreads();

  { // build dec_in into hS[u][r]  (576 elements, one per thread)
    int u = t % 72, r = t / 72;
    float d = dS[r];
    float sp = snapP[r][u], sc = snapC[r][u];
    hS[u*8 + r] = fmaf(d, sc - sp, sp);
  }
  __syncthreads();

  // layer1: 288 x 72  (all 576 threads: n = t>>1, half-row rh)
  float* d1S = rnnS; // [n][8]
  {
    int n = t >> 1, rh = (t & 1)*4;
    float acc[4];
    float b = db1[n];
    acc[0]=b; acc[1]=b; acc[2]=b; acc[3]=b;
    const float4* w4 = (const float4*)(dW1 + n*HH);
    #pragma unroll 2
    for (int k4 = 0; k4 < 18; ++k4) {
      float4 w = w4[k4];
      FMA4(acc, w.x, &hS[(4*k4+0)*8 + rh]);
      FMA4(acc, w.y, &hS[(4*k4+1)*8 + rh]);
      FMA4(acc, w.z, &hS[(4*k4+2)*8 + rh]);
      FMA4(acc, w.w, &hS[(4*k4+3)*8 + rh]);
    }
    #pragma unroll
    for (int j = 0; j < 4; ++j) d1S[n*8 + rh + j] = ftanh(acc[j]);
  }
  __syncthreads();

  // layer2: 288 x 288
  float* d2S = gS;   // [n][8]
  {
    int n = t >> 1, rh = (t & 1)*4;
    float acc[4];
    float b = db2[n];
    acc[0]=b; acc[1]=b; acc[2]=b; acc[3]=b;
    const float4* w4 = (const float4*)(dW2 + n*288);
    #pragma unroll 4
    for (int k4 = 0; k4 < 72; ++k4) {
      float4 w = w4[k4];
      FMA4(acc, w.x, &d1S[(4*k4+0)*8 + rh]);
      FMA4(acc, w.y, &d1S[(4*k4+1)*8 + rh]);
      FMA4(acc, w.z, &d1S[(4*k4+2)*8 + rh]);
      FMA4(acc, w.w, &d1S[(4*k4+3)*8 + rh]);
    }
    #pragma unroll
    for (int j = 0; j < 4; ++j) d2S[n*8 + rh + j] = ftanh(acc[j]);
  }
  __syncthreads();

  // layer3: 8 x 288 (linear) + scatter store
  if (t < 64) {
    int o = t & 7, r = t >> 3;
    float acc3 = db3[o];
    const float* wr = dW3 + o*288;
    #pragma unroll 4
    for (int k = 0; k < 288; ++k) acc3 = fmaf(wr[k], d2S[k*8 + r], acc3);
    out[brS[r]*8 + o] = acc3;
  }
}

extern "C" void kernel_launch(void* const* d_in, const int* in_sizes, int n_in,
                              void* d_out, int out_size, void* d_ws, size_t ws_size,
                              hipStream_t stream) {
  const float* x      = (const float*)d_in[0];
  const float* rnn    = (const float*)d_in[1];
  const float* deltas = (const float*)d_in[2];
  const int*   h_lens = (const int*)  d_in[3];
  const float* W_ih   = (const float*)d_in[4];
  const float* W_hh   = (const float*)d_in[5];
  const float* b_ih   = (const float*)d_in[6];
  const float* b_hh   = (const float*)d_in[7];
  const float* eW1    = (const float*)d_in[8];
  const float* eb1    = (const float*)d_in[9];
  const float* eW2    = (const float*)d_in[10];
  const float* eb2    = (const float*)d_in[11];
  const float* eW3    = (const float*)d_in[12];
  const float* eb3    = (const float*)d_in[13];
  const float* dW1    = (const float*)d_in[14];
  const float* db1    = (const float*)d_in[15];
  const float* dW2    = (const float*)d_in[16];
  const float* db2    = (const float*)d_in[17];
  const float* dW3    = (const float*)d_in[18];
  const float* db3    = (const float*)d_in[19];
  float* out = (float*)d_out;

  int* perm = nullptr;
  if (ws_size >= 2048 * sizeof(int)) {
    perm = (int*)d_ws;
    cfm_sort<<<1, 256, 0, stream>>>(h_lens, perm);
  }
  cfm_main<<<NBLK, NTH, 0, stream>>>(x, rnn, deltas, h_lens, W_ih, W_hh, b_ih, b_hh,
                                     eW1, eb1, eW2, eb2, eW3, eb3,
                                     dW1, db1, dW2, db2, dW3, db3,
                                     perm, out);
}